// Round 4
// baseline (296.539 us; speedup 1.0000x reference)
//
#include <hip/hip_runtime.h>

// Problem constants (fixed by the reference):
//   B=4, C=64, NX=512, NY=512, N = 120000 pillars
#define NXC 512
#define NYC 512
#define CC  64
#define BC  4
#define PLANE (NXC * NYC)   // 262144 floats per (b,c) plane
#define MAXS 128            // staged pillar slots per x-row (row max ~95 for this dataset)
#define PADW 68             // LDS row stride in floats: 16B-aligned, breaks 32-bank alignment

typedef float v4f __attribute__((ext_vector_type(4)));

// ---------------------------------------------------------------------------
// Kernel 1: zero the pillar-index map (4 MB). d_ws is poisoned 0xAA before
// every timed launch, so this must run each call.
__global__ void pp_zero_map(int4* __restrict__ map4, int n4) {
    int i = blockIdx.x * blockDim.x + threadIdx.x;
    if (i < n4) map4[i] = make_int4(0, 0, 0, 0);
}

// ---------------------------------------------------------------------------
// Kernel 2: scatter pillar index n+1 into map[b*NX*NY + x*NY + y].
// coords are unique per (b,x,y) so no write races.
__global__ void pp_build_map(const int* __restrict__ coords, int* __restrict__ map, int N) {
    int n = blockIdx.x * blockDim.x + threadIdx.x;
    if (n >= N) return;
    int4 c = *(const int4*)(coords + 4 * (size_t)n);  // (b, z, y, x)
    map[((size_t)c.x * NXC + c.w) * NYC + c.z] = n + 1;
}

// ---------------------------------------------------------------------------
// Kernel 3: gather with cooperative LDS staging. One block per (b,x) row.
// Phase 1: compact the row's non-empty pillars (LDS atomic counter); encode
//          per-y: slot index, MAXS (=zero slot) for empty, or 0x40000000|n
//          for overflow (>128 pillars in a row — statistically never).
// Phase 2: stage pillar rows into LDS cooperatively: 16 lanes x float4 per
//          row -> 4 contiguous 256B rows per wave load (~8 L1 transactions
//          vs 64 for per-lane scatter).
// Phase 3: per-thread 4x4 register transpose from LDS, coalesced NT float4
//          stores into the c-planes (write-once 256 MiB stream bypasses L2).
__global__ void __launch_bounds__(256) pp_gather(const float* __restrict__ vf,
                                                 const int* __restrict__ map,
                                                 float* __restrict__ out) {
    __shared__ float buf[(MAXS + 1) * PADW];  // slot MAXS = zero row
    __shared__ int   sy[NYC];                 // per-y encoded source
    __shared__ int   pil[MAXS];               // slot -> pillar index
    __shared__ int   cnt;

    int bx = blockIdx.x;            // 0 .. B*NX-1
    int t  = threadIdx.x;           // 0 .. 255

    if (t == 0) cnt = 0;
    if (t < 17) *(v4f*)(&buf[MAXS * PADW + t * 4]) = (v4f){0.f, 0.f, 0.f, 0.f};
    __syncthreads();

    // ---- Phase 1: compact ----
    const int* mrow = map + (size_t)bx * NYC;
    int2 mv = *(const int2*)(mrow + 2 * t);
    {
        int vv[2] = {mv.x, mv.y};
        #pragma unroll
        for (int i = 0; i < 2; ++i) {
            int v = vv[i], e;
            if (v) {
                int s = atomicAdd(&cnt, 1);
                if (s < MAXS) { pil[s] = v - 1; e = s; }
                else          { e = 0x40000000 | (v - 1); }
            } else e = MAXS;  // zero slot
            sy[2 * t + i] = e;
        }
    }
    __syncthreads();

    // ---- Phase 2: stage rows (coalesced) ----
    int K = cnt; if (K > MAXS) K = MAXS;
    int lane16 = t & 15;
    for (int s = t >> 4; s < K; s += 16) {
        v4f f = *(const v4f*)(vf + (size_t)pil[s] * CC + lane16 * 4);
        *(v4f*)(&buf[s * PADW + lane16 * 4]) = f;
    }
    __syncthreads();

    // ---- Phase 3: transpose + coalesced NT stores ----
    int b  = bx >> 9;               // /512
    int x  = bx & (NXC - 1);
    int c0 = (t >> 7) << 5;         // 0 or 32 (c-half)
    int y4 = (t & 127) << 2;        // 0,4,...,508

    int4 e = *(const int4*)(sy + y4);

    float* ob = out + ((size_t)(b * CC + c0) * NXC + x) * NYC + y4;

    #pragma unroll
    for (int cg = 0; cg < 8; ++cg) {
        int c = c0 + cg * 4;
        v4f va, vb, vc, vd;
        // overflow path is wave-uniform-false in practice -> execz-skipped
        va = (e.x & 0x40000000) ? *(const v4f*)(vf + (size_t)(e.x & 0x3FFFFFFF) * CC + c)
                                : *(const v4f*)(&buf[e.x * PADW + c]);
        vb = (e.y & 0x40000000) ? *(const v4f*)(vf + (size_t)(e.y & 0x3FFFFFFF) * CC + c)
                                : *(const v4f*)(&buf[e.y * PADW + c]);
        vc = (e.z & 0x40000000) ? *(const v4f*)(vf + (size_t)(e.z & 0x3FFFFFFF) * CC + c)
                                : *(const v4f*)(&buf[e.z * PADW + c]);
        vd = (e.w & 0x40000000) ? *(const v4f*)(vf + (size_t)(e.w & 0x3FFFFFFF) * CC + c)
                                : *(const v4f*)(&buf[e.w * PADW + c]);
        float* o = ob + (size_t)cg * 4 * PLANE;
        v4f s0 = {va.x, vb.x, vc.x, vd.x};  // plane c
        v4f s1 = {va.y, vb.y, vc.y, vd.y};  // plane c+1
        v4f s2 = {va.z, vb.z, vc.z, vd.z};  // plane c+2
        v4f s3 = {va.w, vb.w, vc.w, vd.w};  // plane c+3
        __builtin_nontemporal_store(s0, (v4f*)(o));
        __builtin_nontemporal_store(s1, (v4f*)(o + PLANE));
        __builtin_nontemporal_store(s2, (v4f*)(o + 2 * (size_t)PLANE));
        __builtin_nontemporal_store(s3, (v4f*)(o + 3 * (size_t)PLANE));
    }
}

extern "C" void kernel_launch(void* const* d_in, const int* in_sizes, int n_in,
                              void* d_out, int out_size, void* d_ws, size_t ws_size,
                              hipStream_t stream) {
    const float* vf     = (const float*)d_in[0];
    const int*   coords = (const int*)d_in[1];
    // d_in[2] = batch_size scalar (fixed at 4; dims are compile-time constants)

    float* out = (float*)d_out;
    int*   map = (int*)d_ws;                       // 4 MB: B*NX*NY int32

    const int N = in_sizes[0] / CC;                // 120000 pillars
    const int MAPN  = BC * NXC * NYC;              // 1,048,576
    const int MAPN4 = MAPN / 4;                    // 262,144 int4s

    pp_zero_map<<<(MAPN4 + 255) / 256, 256, 0, stream>>>((int4*)map, MAPN4);
    pp_build_map<<<(N + 255) / 256, 256, 0, stream>>>(coords, map, N);
    pp_gather<<<BC * NXC, 256, 0, stream>>>(vf, map, out);
}